// Round 3
// baseline (21023.552 us; speedup 1.0000x reference)
//
#include <hip/hip_runtime.h>
#include <cmath>

#define HID    1024
#define VOCAB  32000
#define TLEN   128
#define FC_NBLK 500

typedef __attribute__((ext_vector_type(8))) short bf16x8;
typedef __attribute__((ext_vector_type(4))) float f32x4;

// ---------------- bf16 split helpers ----------------
__device__ __forceinline__ unsigned short bf_hi(float f) {
  unsigned u = __float_as_uint(f);
  return (unsigned short)((u + 0x7fffu + ((u >> 16) & 1u)) >> 16);
}
__device__ __forceinline__ float bf_f(unsigned short h) {
  return __uint_as_float(((unsigned)h) << 16);
}
__device__ __forceinline__ void split2(float f, unsigned short& hi, unsigned short& lo) {
  hi = bf_hi(f);
  lo = bf_hi(f - bf_f(hi));
}

// ================= workspace layout (bytes) =================
#define OFF_FCW_HI 0ULL
#define OFF_FCW_LO 65536000ULL
#define OFF_WIH_HI 131072000ULL
#define OFF_WIH_LO 137363456ULL
#define OFF_WHH_HI 143654912ULL
#define OFF_WHH_LO 149946368ULL
#define OFF_GBUF   156237824ULL     // 16 x 64 x 3072 f32
#define OFF_H32    168820736ULL
#define OFF_XHI    169082880ULL
#define OFF_XLO    169213952ULL
#define OFF_HHI    169345024ULL
#define OFF_HLO    169476096ULL
#define OFF_PVB    169607168ULL     // [500][64] f32
#define OFF_PIB    169735168ULL     // [500][64] i32
#define OFF_CTR    169863168ULL     // [128] u32
#define WS_NEED    169863680ULL

// ---------------- one-time weight split ----------------
__global__ __launch_bounds__(256) void k_split(const float* __restrict__ src,
                                               unsigned short* __restrict__ hi,
                                               unsigned short* __restrict__ lo, int n4) {
  int i = blockIdx.x * 256 + threadIdx.x;
  const int stride = gridDim.x * 256;
  for (; i < n4; i += stride) {
    float4 v = ((const float4*)src)[i];
    ushort4 h, l;
    split2(v.x, h.x, l.x);
    split2(v.y, h.y, l.y);
    split2(v.z, h.z, l.z);
    split2(v.w, h.w, l.w);
    ((ushort4*)hi)[i] = h;
    ((ushort4*)lo)[i] = l;
  }
}

// ---------------- one-time state init (t=0 x and h) ----------------
__global__ __launch_bounds__(256) void k_init(
    const float* __restrict__ enc, const int* __restrict__ tt,
    const float* __restrict__ emb,
    unsigned short* __restrict__ xhi, unsigned short* __restrict__ xlo,
    float* __restrict__ h32, unsigned short* __restrict__ hhi,
    unsigned short* __restrict__ hlo) {
  const int r = blockIdx.x;
  const int tid = threadIdx.x;      // 256 = HID/4
  const int tok = tt[r * TLEN];
  float4 v = ((const float4*)(emb + (size_t)tok * HID))[tid];
  ushort4 h4, l4;
  split2(v.x, h4.x, l4.x); split2(v.y, h4.y, l4.y);
  split2(v.z, h4.z, l4.z); split2(v.w, h4.w, l4.w);
  ((ushort4*)(xhi + (size_t)r * HID))[tid] = h4;
  ((ushort4*)(xlo + (size_t)r * HID))[tid] = l4;
  float4 u = ((const float4*)(enc + (size_t)r * HID))[tid];
  ((float4*)(h32 + (size_t)r * HID))[tid] = u;
  split2(u.x, h4.x, l4.x); split2(u.y, h4.y, l4.y);
  split2(u.z, h4.z, l4.z); split2(u.w, h4.w, l4.w);
  ((ushort4*)(hhi + (size_t)r * HID))[tid] = h4;
  ((ushort4*)(hlo + (size_t)r * HID))[tid] = l4;
}

// ---------------- gates GEMM, K split 8 ways ----------------
// grid 768 = 2 sides x 48 colblocks x 8 ksplits, 256 thr (4 waves x 16 cols)
__global__ __launch_bounds__(256) void k_gates(
    const unsigned short* __restrict__ xhi, const unsigned short* __restrict__ xlo,
    const unsigned short* __restrict__ hhi, const unsigned short* __restrict__ hlo,
    const unsigned short* __restrict__ wihhi, const unsigned short* __restrict__ wihlo,
    const unsigned short* __restrict__ whhhi, const unsigned short* __restrict__ whhlo,
    float* __restrict__ gbuf) {
  const int bid = blockIdx.x;
  const int side = (bid >= 384) ? 1 : 0;
  const int b2 = bid - side * 384;
  const int cb = b2 >> 3, ks = b2 & 7;
  const unsigned short* Ahi = side ? hhi : xhi;
  const unsigned short* Alo = side ? hlo : xlo;
  const unsigned short* Bhi = side ? whhhi : wihhi;
  const unsigned short* Blo = side ? whhlo : wihlo;
  const int tid = threadIdx.x, w = tid >> 6, lane = tid & 63;
  const int n0 = cb * 64 + w * 16;
  const int l15 = lane & 15, kg = (lane >> 4) * 8;
  const int kb = ks * 128 + kg;
  const unsigned short* bph = Bhi + (size_t)(n0 + l15) * HID + kb;
  const unsigned short* bpl = Blo + (size_t)(n0 + l15) * HID + kb;
  const unsigned short* aph = Ahi + (size_t)l15 * HID + kb;
  const unsigned short* apl = Alo + (size_t)l15 * HID + kb;
  f32x4 acc[4] = {};
#pragma unroll
  for (int k0 = 0; k0 < 128; k0 += 32) {
    bf16x8 bh = *(const bf16x8*)(bph + k0);
    bf16x8 bl = *(const bf16x8*)(bpl + k0);
#pragma unroll
    for (int m = 0; m < 4; m++) {
      bf16x8 a1 = *(const bf16x8*)(aph + (size_t)m * 16 * HID + k0);
      bf16x8 a2 = *(const bf16x8*)(apl + (size_t)m * 16 * HID + k0);
      acc[m] = __builtin_amdgcn_mfma_f32_16x16x32_bf16(a1, bh, acc[m], 0, 0, 0);
      acc[m] = __builtin_amdgcn_mfma_f32_16x16x32_bf16(a2, bh, acc[m], 0, 0, 0);
      acc[m] = __builtin_amdgcn_mfma_f32_16x16x32_bf16(a1, bl, acc[m], 0, 0, 0);
    }
  }
  float* C = gbuf + (size_t)(side * 8 + ks) * 64 * 3072;
  const int col = n0 + l15;
#pragma unroll
  for (int m = 0; m < 4; m++)
#pragma unroll
    for (int q = 0; q < 4; q++)
      C[(size_t)(m * 16 + (lane >> 4) * 4 + q) * 3072 + col] = acc[m][q];
}

// ---------------- combine: sum partials + GRU + h split + ctr reset ----------------
__global__ __launch_bounds__(256) void k_combine(
    const float* __restrict__ gbuf, const float* __restrict__ b_ih,
    const float* __restrict__ b_hh, float* __restrict__ h32,
    unsigned short* __restrict__ hhi, unsigned short* __restrict__ hlo,
    unsigned int* __restrict__ ctr, int t) {
  const int idx = blockIdx.x * 256 + threadIdx.x;  // 64 x 1024
  const int r = idx >> 10, j = idx & 1023;
  float ir = b_ih[j], iz = b_ih[1024 + j], inn = b_ih[2048 + j];
  float hr = b_hh[j], hz = b_hh[1024 + j], hn = b_hh[2048 + j];
#pragma unroll
  for (int ks = 0; ks < 8; ks++) {
    const float* g0 = gbuf + ((size_t)ks * 64 + r) * 3072;
    const float* g1 = gbuf + ((size_t)(8 + ks) * 64 + r) * 3072;
    ir += g0[j]; iz += g0[1024 + j]; inn += g0[2048 + j];
    hr += g1[j]; hz += g1[1024 + j]; hn += g1[2048 + j];
  }
  float rg = 1.f / (1.f + expf(-(ir + hr)));
  float zg = 1.f / (1.f + expf(-(iz + hz)));
  float nn = tanhf(inn + rg * hn);
  float hp = h32[(size_t)r * HID + j];
  float h = (1.f - zg) * nn + zg * hp;
  h32[(size_t)r * HID + j] = h;
  unsigned short hi_, lo_;
  split2(h, hi_, lo_);
  hhi[(size_t)r * HID + j] = hi_;
  hlo[(size_t)r * HID + j] = lo_;
  if (idx == 0) ctr[t] = 0;
}

// ---------------- FC GEMM + logits + argmax (last-block finalize + gather) ----------------
// grid 500, 256 thr = 4 waves, each wave: 64 rows x 64 cols, K-quarter 256
__global__ __launch_bounds__(256, 2) void k_fc(
    const unsigned short* __restrict__ ahi, const unsigned short* __restrict__ alo,
    const unsigned short* __restrict__ fwhi, const unsigned short* __restrict__ fwlo,
    const float* __restrict__ fc_b, const float* __restrict__ emb,
    float* __restrict__ out, float* __restrict__ pvb, int* __restrict__ pib,
    unsigned short* __restrict__ xhi, unsigned short* __restrict__ xlo,
    unsigned int* __restrict__ ctr, int t) {
  __shared__ float pred[4][64][68];   // padded: b128-friendly, ~69.6 KB
  __shared__ int s_tok[64];
  __shared__ int s_last;
  const int bid = blockIdx.x;
  const int tid = threadIdx.x;
  const int wv = tid >> 6;            // K-quarter id
  const int lane = tid & 63;
  const int l15 = lane & 15;
  const int kg = (lane >> 4) * 8;
  const int kb = wv * 256 + kg;
  const int c0 = bid * 64;
  const unsigned short* bph = fwhi + (size_t)(c0 + l15) * HID + kb;
  const unsigned short* bpl = fwlo + (size_t)(c0 + l15) * HID + kb;
  const unsigned short* aph = ahi + (size_t)l15 * HID + kb;
  const unsigned short* apl = alo + (size_t)l15 * HID + kb;
  f32x4 acc[4][4] = {};   // [m (rows)][n (cols)]
  for (int k0 = 0; k0 < 256; k0 += 32) {
    bf16x8 bh[4], bl[4];
#pragma unroll
    for (int n = 0; n < 4; n++) {
      bh[n] = *(const bf16x8*)(bph + (size_t)n * 16 * HID + k0);
      bl[n] = *(const bf16x8*)(bpl + (size_t)n * 16 * HID + k0);
    }
#pragma unroll
    for (int m = 0; m < 4; m++) {
      bf16x8 a1 = *(const bf16x8*)(aph + (size_t)m * 16 * HID + k0);
      bf16x8 a2 = *(const bf16x8*)(apl + (size_t)m * 16 * HID + k0);
#pragma unroll
      for (int n = 0; n < 4; n++) {
        acc[m][n] = __builtin_amdgcn_mfma_f32_16x16x32_bf16(a1, bh[n], acc[m][n], 0, 0, 0);
        acc[m][n] = __builtin_amdgcn_mfma_f32_16x16x32_bf16(a2, bh[n], acc[m][n], 0, 0, 0);
        acc[m][n] = __builtin_amdgcn_mfma_f32_16x16x32_bf16(a1, bl[n], acc[m][n], 0, 0, 0);
      }
    }
  }
  // dump K-quarter partials
#pragma unroll
  for (int m = 0; m < 4; m++)
#pragma unroll
    for (int n = 0; n < 4; n++)
#pragma unroll
      for (int q = 0; q < 4; q++)
        pred[wv][m * 16 + (lane >> 4) * 4 + q][n * 16 + l15] = acc[m][n][q];
  __syncthreads();
  // epilogue: thread -> row = tid>>2, col quadrant = (tid&3)*16
  const int row = tid >> 2;
  const int cq = (tid & 3) * 16;
  float v[16];
#pragma unroll
  for (int c4 = 0; c4 < 4; c4++) {
    float4 s0 = *(const float4*)&pred[0][row][cq + c4 * 4];
    float4 s1 = *(const float4*)&pred[1][row][cq + c4 * 4];
    float4 s2 = *(const float4*)&pred[2][row][cq + c4 * 4];
    float4 s3 = *(const float4*)&pred[3][row][cq + c4 * 4];
    v[c4 * 4 + 0] = s0.x + s1.x + s2.x + s3.x + fc_b[c0 + cq + c4 * 4 + 0];
    v[c4 * 4 + 1] = s0.y + s1.y + s2.y + s3.y + fc_b[c0 + cq + c4 * 4 + 1];
    v[c4 * 4 + 2] = s0.z + s1.z + s2.z + s3.z + fc_b[c0 + cq + c4 * 4 + 2];
    v[c4 * 4 + 3] = s0.w + s1.w + s2.w + s3.w + fc_b[c0 + cq + c4 * 4 + 3];
  }
  float* op = out + ((size_t)row * TLEN + t) * VOCAB + c0 + cq;
#pragma unroll
  for (int c = 0; c < 16; c += 4)
    *(float4*)(op + c) = make_float4(v[c], v[c + 1], v[c + 2], v[c + 3]);
  // per-thread argmax over its 16 cols (ascending scan keeps smallest index on ties)
  float bv = v[0]; int bi = c0 + cq;
#pragma unroll
  for (int c = 1; c < 16; c++)
    if (v[c] > bv) { bv = v[c]; bi = c0 + cq + c; }
  // merge 4 threads covering same row
#pragma unroll
  for (int d = 1; d < 4; d <<= 1) {
    float ov = __shfl_xor(bv, d);
    int oi = __shfl_xor(bi, d);
    if (ov > bv || (ov == bv && oi < bi)) { bv = ov; bi = oi; }
  }
  if ((tid & 3) == 0) { pvb[bid * 64 + row] = bv; pib[bid * 64 + row] = bi; }
  __syncthreads();
  if (tid == 0) {
    __threadfence();
    unsigned old = atomicAdd(&ctr[t], 1u);
    s_last = (old == FC_NBLK - 1) ? 1 : 0;
  }
  __syncthreads();
  if (s_last) {
    __threadfence();
    const int r2 = tid >> 2, o = tid & 3;
    float bv2 = -INFINITY; int bi2 = 0x7fffffff;
    for (int j = o; j < FC_NBLK; j += 4) {
      float vv = pvb[j * 64 + r2]; int ii = pib[j * 64 + r2];
      if (vv > bv2 || (vv == bv2 && ii < bi2)) { bv2 = vv; bi2 = ii; }
    }
#pragma unroll
    for (int d = 1; d < 4; d <<= 1) {
      float ov = __shfl_xor(bv2, d);
      int oi = __shfl_xor(bi2, d);
      if (ov > bv2 || (ov == bv2 && oi < bi2)) { bv2 = ov; bi2 = oi; }
    }
    if (o == 0) s_tok[r2] = bi2;
    __syncthreads();
    // gather next x = emb[tok] and split (64 rows x 256 float4)
    for (int i = tid; i < 64 * 256; i += 256) {
      int rr = i >> 8, k4 = i & 255;
      float4 vv = *(const float4*)(emb + (size_t)s_tok[rr] * HID + k4 * 4);
      ushort4 h4, l4;
      split2(vv.x, h4.x, l4.x); split2(vv.y, h4.y, l4.y);
      split2(vv.z, h4.z, l4.z); split2(vv.w, h4.w, l4.w);
      *(ushort4*)(xhi + (size_t)rr * HID + k4 * 4) = h4;
      *(ushort4*)(xlo + (size_t)rr * HID + k4 * 4) = l4;
    }
  }
}

// ======================= fp32 fallback path (round-1, known-good) =======================
#define O_FC_NCB 250
#define O_X2T_OFF  0
#define O_GBUF_OFF (2048*64)
#define O_PV_OFF   (O_GBUF_OFF + 8*64*4096)
#define O_PI_OFF   (O_PV_OFF + 64*O_FC_NCB)

__global__ __launch_bounds__(256) void o_prep(
    const float* __restrict__ enc, const int* __restrict__ tt,
    const float* __restrict__ emb, float* __restrict__ X2T,
    const float* __restrict__ pv, const int* __restrict__ pi, int t) {
  const int r = blockIdx.x;
  const int tid = threadIdx.x;
  __shared__ int s_tok;
  __shared__ float red_v[256];
  __shared__ int red_i[256];
  if (t == 0) {
    if (tid == 0) s_tok = tt[r * TLEN];
  } else {
    float v = -INFINITY; int idx = 0x7fffffff;
    if (tid < O_FC_NCB) { v = pv[r * O_FC_NCB + tid]; idx = pi[r * O_FC_NCB + tid]; }
    red_v[tid] = v; red_i[tid] = idx;
    __syncthreads();
    for (int s = 128; s > 0; s >>= 1) {
      if (tid < s) {
        float v2 = red_v[tid + s]; int i2 = red_i[tid + s];
        if (v2 > red_v[tid] || (v2 == red_v[tid] && i2 < red_i[tid])) {
          red_v[tid] = v2; red_i[tid] = i2;
        }
      }
      __syncthreads();
    }
    if (tid == 0) s_tok = red_i[0];
  }
  __syncthreads();
  const int tok = s_tok;
  for (int k = tid; k < HID; k += 256)
    X2T[(size_t)k * 64 + r] = emb[(size_t)tok * HID + k];
  if (t == 0) {
    for (int k = tid; k < HID; k += 256)
      X2T[(size_t)(HID + k) * 64 + r] = enc[r * HID + k];
  }
}

__global__ __launch_bounds__(256) void o_gates(
    const float* __restrict__ w_ih, const float* __restrict__ w_hh,
    const float* __restrict__ X2T, float* __restrict__ gbuf) {
  const int cb = blockIdx.x & 31;
  const int s  = blockIdx.x >> 5;
  const int g  = cb >> 3;
  if (g == 2 && s >= 4) return;
  if (g == 3 && s < 4) return;
  const int tid  = threadIdx.x;
  const int w    = __builtin_amdgcn_readfirstlane(tid >> 6);
  const int lane = tid & 63;
  const int r0   = (w >> 1) * 32;
  const int cc   = cb * 128 + (w & 1) * 64 + lane;
  const int j    = cc & 1023;
  const float* Bmat; int kk0;
  if (s < 4) { Bmat = w_ih; kk0 = s * 256; }
  else       { Bmat = w_hh; kk0 = (s - 4) * 256; }
  int brow;
  if (g == 0) brow = j;
  else if (g == 1) brow = 1024 + j;
  else brow = 2048 + j;
  const float* Bp = Bmat + (size_t)brow * HID + kk0;
  const float* Ap = X2T + (size_t)(s * 256) * 64 + r0;
  float acc[32];
#pragma unroll
  for (int i = 0; i < 32; i++) acc[i] = 0.f;
  for (int k = 0; k < 256; k += 4) {
    float4 b = *(const float4*)(Bp + k);
#pragma unroll
    for (int kk = 0; kk < 4; kk++) {
      const float bk = (&b.x)[kk];
      const float* a = Ap + (size_t)(k + kk) * 64;
#pragma unroll
      for (int i = 0; i < 32; i++) acc[i] = fmaf(a[i], bk, acc[i]);
    }
  }
  float* C = gbuf + (size_t)s * (64 * 4096) + cc;
#pragma unroll
  for (int i = 0; i < 32; i++) C[(size_t)(r0 + i) * 4096] = acc[i];
}

__global__ __launch_bounds__(256) void o_combine(
    const float* __restrict__ b_ih, const float* __restrict__ b_hh,
    const float* __restrict__ gbuf, float* __restrict__ X2T) {
  const int idx = blockIdx.x * 256 + threadIdx.x;
  const int r = idx >> 10;
  const int j = idx & 1023;
  const size_t SS = (size_t)64 * 4096;
  float sr  = b_ih[j] + b_hh[j];
  float sz  = b_ih[1024 + j] + b_hh[1024 + j];
  float inn = b_ih[2048 + j];
  float hn  = b_hh[2048 + j];
#pragma unroll
  for (int s = 0; s < 8; s++) {
    const float* gs = gbuf + s * SS + (size_t)r * 4096;
    sr += gs[j];
    sz += gs[1024 + j];
    if (s < 4) inn += gs[2048 + j]; else hn += gs[3072 + j];
  }
  float rg = 1.f / (1.f + expf(-sr));
  float zg = 1.f / (1.f + expf(-sz));
  float n  = tanhf(inn + rg * hn);
  float hp = X2T[(size_t)(1024 + j) * 64 + r];
  float h  = (1.f - zg) * n + zg * hp;
  X2T[(size_t)(1024 + j) * 64 + r] = h;
}

__global__ __launch_bounds__(256) void o_fc(
    const float* __restrict__ fc_w, const float* __restrict__ fc_b,
    const float* __restrict__ hT, float* __restrict__ out,
    float* __restrict__ pv, int* __restrict__ pi, int t) {
  const int tid  = threadIdx.x;
  const int w    = __builtin_amdgcn_readfirstlane(tid >> 6);
  const int lane = tid & 63;
  const int r0   = (w >> 1) * 32;
  const int col  = blockIdx.x * 128 + (w & 1) * 64 + lane;
  const float* Bp = fc_w + (size_t)col * HID;
  float acc[32];
#pragma unroll
  for (int i = 0; i < 32; i++) acc[i] = 0.f;
  for (int k = 0; k < HID; k += 4) {
    float4 b = *(const float4*)(Bp + k);
#pragma unroll
    for (int kk = 0; kk < 4; kk++) {
      const float bk = (&b.x)[kk];
      const float* a = hT + (size_t)(k + kk) * 64 + r0;
#pragma unroll
      for (int i = 0; i < 32; i++) acc[i] = fmaf(a[i], bk, acc[i]);
    }
  }
  const float bias = fc_b[col];
#pragma unroll
  for (int i = 0; i < 32; i++) {
    float v = acc[i] + bias;
    acc[i] = v;
    out[((size_t)(r0 + i) * TLEN + t) * VOCAB + col] = v;
  }
  __shared__ float sv[2][64];
  __shared__ int   si[2][64];
#pragma unroll 4
  for (int i = 0; i < 32; i++) {
    float v = acc[i]; int idx = col;
#pragma unroll
    for (int d = 32; d > 0; d >>= 1) {
      float v2 = __shfl_xor(v, d);
      int i2   = __shfl_xor(idx, d);
      if (v2 > v || (v2 == v && i2 < idx)) { v = v2; idx = i2; }
    }
    if (lane == 0) { sv[w & 1][r0 + i] = v; si[w & 1][r0 + i] = idx; }
  }
  __syncthreads();
  if (tid < 64) {
    float v = sv[0][tid]; int idx = si[0][tid];
    float v2 = sv[1][tid]; int i2 = si[1][tid];
    if (v2 > v || (v2 == v && i2 < idx)) { v = v2; idx = i2; }
    pv[tid * O_FC_NCB + blockIdx.x] = v;
    pi[tid * O_FC_NCB + blockIdx.x] = idx;
  }
}

// =======================================================================
extern "C" void kernel_launch(void* const* d_in, const int* in_sizes, int n_in,
                              void* d_out, int out_size, void* d_ws, size_t ws_size,
                              hipStream_t stream) {
  const float* enc  = (const float*)d_in[0];
  const int*   tt   = (const int*)d_in[1];
  const float* emb  = (const float*)d_in[2];
  const float* w_ih = (const float*)d_in[3];
  const float* w_hh = (const float*)d_in[4];
  const float* b_ih = (const float*)d_in[5];
  const float* b_hh = (const float*)d_in[6];
  const float* fc_w = (const float*)d_in[7];
  const float* fc_b = (const float*)d_in[8];
  float* out = (float*)d_out;

  if (ws_size >= WS_NEED) {
    char* ws = (char*)d_ws;
    unsigned short* fcw_hi = (unsigned short*)(ws + OFF_FCW_HI);
    unsigned short* fcw_lo = (unsigned short*)(ws + OFF_FCW_LO);
    unsigned short* wih_hi = (unsigned short*)(ws + OFF_WIH_HI);
    unsigned short* wih_lo = (unsigned short*)(ws + OFF_WIH_LO);
    unsigned short* whh_hi = (unsigned short*)(ws + OFF_WHH_HI);
    unsigned short* whh_lo = (unsigned short*)(ws + OFF_WHH_LO);
    float* gbuf = (float*)(ws + OFF_GBUF);
    float* h32  = (float*)(ws + OFF_H32);
    unsigned short* xhi = (unsigned short*)(ws + OFF_XHI);
    unsigned short* xlo = (unsigned short*)(ws + OFF_XLO);
    unsigned short* hhi = (unsigned short*)(ws + OFF_HHI);
    unsigned short* hlo = (unsigned short*)(ws + OFF_HLO);
    float* pvb = (float*)(ws + OFF_PVB);
    int*   pib = (int*)(ws + OFF_PIB);
    unsigned int* ctr = (unsigned int*)(ws + OFF_CTR);

    k_split<<<4096, 256, 0, stream>>>(fc_w, fcw_hi, fcw_lo, VOCAB * HID / 4);
    k_split<<<1536, 256, 0, stream>>>(w_ih, wih_hi, wih_lo, 3 * HID * HID / 4);
    k_split<<<1536, 256, 0, stream>>>(w_hh, whh_hi, whh_lo, 3 * HID * HID / 4);
    k_init<<<64, 256, 0, stream>>>(enc, tt, emb, xhi, xlo, h32, hhi, hlo);

    for (int t = 0; t < TLEN; t++) {
      k_gates<<<768, 256, 0, stream>>>(xhi, xlo, hhi, hlo, wih_hi, wih_lo,
                                       whh_hi, whh_lo, gbuf);
      k_combine<<<256, 256, 0, stream>>>(gbuf, b_ih, b_hh, h32, hhi, hlo, ctr, t);
      k_fc<<<FC_NBLK, 256, 0, stream>>>(hhi, hlo, fcw_hi, fcw_lo, fc_b, emb, out,
                                        pvb, pib, xhi, xlo, ctr, t);
    }
  } else {
    float* ws = (float*)d_ws;
    float* X2T  = ws + O_X2T_OFF;
    float* gbuf = ws + O_GBUF_OFF;
    float* pv   = ws + O_PV_OFF;
    int*   pi   = (int*)(ws + O_PI_OFF);
    for (int t = 0; t < TLEN; t++) {
      o_prep<<<64, 256, 0, stream>>>(enc, tt, emb, X2T, pv, pi, t);
      o_gates<<<256, 256, 0, stream>>>(w_ih, w_hh, X2T, gbuf);
      o_combine<<<256, 256, 0, stream>>>(b_ih, b_hh, gbuf, X2T);
      o_fc<<<O_FC_NCB, 256, 0, stream>>>(fc_w, fc_b, X2T + (size_t)HID * 64, out, pv, pi, t);
    }
  }
}

// Round 4
// 8733.096 us; speedup vs baseline: 2.4073x; 2.4073x over previous
//
#include <hip/hip_runtime.h>
#include <cmath>

#define HID    1024
#define VOCAB  32000
#define TLEN   128
#define FC_NBLK 500
#define GH_NBLK 384              // 48 coltiles x 8 ksplit

typedef __attribute__((ext_vector_type(8))) short bf16x8;
typedef __attribute__((ext_vector_type(4))) float f32x4;

// ---------------- bf16 split helpers ----------------
__device__ __forceinline__ unsigned short bf_hi(float f) {
  unsigned u = __float_as_uint(f);
  return (unsigned short)((u + 0x7fffu + ((u >> 16) & 1u)) >> 16);
}
__device__ __forceinline__ float bf_f(unsigned short h) {
  return __uint_as_float(((unsigned)h) << 16);
}
__device__ __forceinline__ void split2(float f, unsigned short& hi, unsigned short& lo) {
  hi = bf_hi(f);
  lo = bf_hi(f - bf_f(hi));
}

// ================= workspace layout (bytes) =================
#define OFF_FCW_HI 0ULL
#define OFF_FCW_LO 65536000ULL
#define OFF_WIH_HI 131072000ULL
#define OFF_WIH_LO 137363456ULL
#define OFF_WHH_HI 143654912ULL
#define OFF_WHH_LO 149946368ULL
#define OFF_GBUF   156237824ULL     // 16 x 64 x 3072 f32
#define OFF_H32    168820736ULL
#define OFF_XHI    169082880ULL
#define OFF_XLO    169213952ULL
#define OFF_HHI    169345024ULL
#define OFF_HLO    169476096ULL
#define OFF_PVB    169607168ULL     // [64][500] f32
#define OFF_PIB    169735168ULL     // [64][500] i32
#define WS_NEED    169863680ULL

// ---------------- one-time weight split ----------------
__global__ __launch_bounds__(256) void k_split(const float* __restrict__ src,
                                               unsigned short* __restrict__ hi,
                                               unsigned short* __restrict__ lo, int n4) {
  int i = blockIdx.x * 256 + threadIdx.x;
  const int stride = gridDim.x * 256;
  for (; i < n4; i += stride) {
    float4 v = ((const float4*)src)[i];
    ushort4 h, l;
    split2(v.x, h.x, l.x);
    split2(v.y, h.y, l.y);
    split2(v.z, h.z, l.z);
    split2(v.w, h.w, l.w);
    ((ushort4*)hi)[i] = h;
    ((ushort4*)lo)[i] = l;
  }
}

// ---------------- one-time state init (t=0 x and h) ----------------
__global__ __launch_bounds__(256) void k_init(
    const float* __restrict__ enc, const int* __restrict__ tt,
    const float* __restrict__ emb,
    unsigned short* __restrict__ xhi, unsigned short* __restrict__ xlo,
    float* __restrict__ h32, unsigned short* __restrict__ hhi,
    unsigned short* __restrict__ hlo) {
  const int r = blockIdx.x;
  const int tid = threadIdx.x;      // 256 = HID/4
  const int tok = tt[r * TLEN];
  float4 v = ((const float4*)(emb + (size_t)tok * HID))[tid];
  ushort4 h4, l4;
  split2(v.x, h4.x, l4.x); split2(v.y, h4.y, l4.y);
  split2(v.z, h4.z, l4.z); split2(v.w, h4.w, l4.w);
  ((ushort4*)(xhi + (size_t)r * HID))[tid] = h4;
  ((ushort4*)(xlo + (size_t)r * HID))[tid] = l4;
  float4 u = ((const float4*)(enc + (size_t)r * HID))[tid];
  ((float4*)(h32 + (size_t)r * HID))[tid] = u;
  split2(u.x, h4.x, l4.x); split2(u.y, h4.y, l4.y);
  split2(u.z, h4.z, l4.z); split2(u.w, h4.w, l4.w);
  ((ushort4*)(hhi + (size_t)r * HID))[tid] = h4;
  ((ushort4*)(hlo + (size_t)r * HID))[tid] = l4;
}

// ---------------- shared gates tile: 64 cols x 128 k, 4 waves x 16 cols ----------------
__device__ __forceinline__ void gates_tile(
    const unsigned short* __restrict__ Ahi, const unsigned short* __restrict__ Alo,
    const unsigned short* __restrict__ Bhi, const unsigned short* __restrict__ Blo,
    float* __restrict__ C, int cb, int ks, int tid) {
  const int w = tid >> 6, lane = tid & 63;
  const int n0 = cb * 64 + w * 16;
  const int l15 = lane & 15, kg = (lane >> 4) * 8;
  const int kb = ks * 128 + kg;
  const unsigned short* bph = Bhi + (size_t)(n0 + l15) * HID + kb;
  const unsigned short* bpl = Blo + (size_t)(n0 + l15) * HID + kb;
  const unsigned short* aph = Ahi + (size_t)l15 * HID + kb;
  const unsigned short* apl = Alo + (size_t)l15 * HID + kb;
  f32x4 acc[4] = {};
#pragma unroll
  for (int k0 = 0; k0 < 128; k0 += 32) {
    bf16x8 bh = *(const bf16x8*)(bph + k0);
    bf16x8 bl = *(const bf16x8*)(bpl + k0);
#pragma unroll
    for (int m = 0; m < 4; m++) {
      bf16x8 a1 = *(const bf16x8*)(aph + (size_t)m * 16 * HID + k0);
      bf16x8 a2 = *(const bf16x8*)(apl + (size_t)m * 16 * HID + k0);
      acc[m] = __builtin_amdgcn_mfma_f32_16x16x32_bf16(a1, bh, acc[m], 0, 0, 0);
      acc[m] = __builtin_amdgcn_mfma_f32_16x16x32_bf16(a2, bh, acc[m], 0, 0, 0);
      acc[m] = __builtin_amdgcn_mfma_f32_16x16x32_bf16(a1, bl, acc[m], 0, 0, 0);
    }
  }
  const int col = n0 + l15;
#pragma unroll
  for (int m = 0; m < 4; m++)
#pragma unroll
    for (int q = 0; q < 4; q++)
      C[(size_t)(m * 16 + (lane >> 4) * 4 + q) * 3072 + col] = acc[m][q];
}

// gi: x @ w_ih^T  (slices 0..7)
__global__ __launch_bounds__(256) void k_gi(
    const unsigned short* __restrict__ xhi, const unsigned short* __restrict__ xlo,
    const unsigned short* __restrict__ wihhi, const unsigned short* __restrict__ wihlo,
    float* __restrict__ gbuf) {
  const int cb = blockIdx.x >> 3, ks = blockIdx.x & 7;
  gates_tile(xhi, xlo, wihhi, wihlo, gbuf + (size_t)ks * 64 * 3072, cb, ks, threadIdx.x);
}

// gh: h @ w_hh^T  (slices 8..15) — standalone, used for t=0 only
__global__ __launch_bounds__(256) void k_gh(
    const unsigned short* __restrict__ hhi, const unsigned short* __restrict__ hlo,
    const unsigned short* __restrict__ whhhi, const unsigned short* __restrict__ whhlo,
    float* __restrict__ gbuf) {
  const int cb = blockIdx.x >> 3, ks = blockIdx.x & 7;
  gates_tile(hhi, hlo, whhhi, whhlo, gbuf + (size_t)(8 + ks) * 64 * 3072, cb, ks, threadIdx.x);
}

// ---------------- combine: sum partials + GRU + h split ----------------
__global__ __launch_bounds__(256) void k_combine(
    const float* __restrict__ gbuf, const float* __restrict__ b_ih,
    const float* __restrict__ b_hh, float* __restrict__ h32,
    unsigned short* __restrict__ hhi, unsigned short* __restrict__ hlo) {
  const int idx = blockIdx.x * 256 + threadIdx.x;  // 64 x 1024
  const int r = idx >> 10, j = idx & 1023;
  float ir = b_ih[j], iz = b_ih[1024 + j], inn = b_ih[2048 + j];
  float hr = b_hh[j], hz = b_hh[1024 + j], hn = b_hh[2048 + j];
#pragma unroll
  for (int ks = 0; ks < 8; ks++) {
    const float* g0 = gbuf + ((size_t)ks * 64 + r) * 3072;
    const float* g1 = gbuf + ((size_t)(8 + ks) * 64 + r) * 3072;
    ir += g0[j]; iz += g0[1024 + j]; inn += g0[2048 + j];
    hr += g1[j]; hz += g1[1024 + j]; hn += g1[2048 + j];
  }
  float rg = 1.f / (1.f + expf(-(ir + hr)));
  float zg = 1.f / (1.f + expf(-(iz + hz)));
  float nn = tanhf(inn + rg * hn);
  float hp = h32[(size_t)r * HID + j];
  float h = (1.f - zg) * nn + zg * hp;
  h32[(size_t)r * HID + j] = h;
  unsigned short hi_, lo_;
  split2(h, hi_, lo_);
  hhi[(size_t)r * HID + j] = hi_;
  hlo[(size_t)r * HID + j] = lo_;
}

// ---------------- prep: finalize argmax over 500 block-partials + gather/split x ----------------
// grid 64 (one block per batch row)
__global__ __launch_bounds__(256) void k_prep(
    const float* __restrict__ pvb, const int* __restrict__ pib,
    const float* __restrict__ emb,
    unsigned short* __restrict__ xhi, unsigned short* __restrict__ xlo) {
  const int r = blockIdx.x;
  const int tid = threadIdx.x;
  __shared__ float rv[256];
  __shared__ int ri[256];
  __shared__ int s_tok;
  float v = -INFINITY; int ix = 0x7fffffff;
  for (int j = tid; j < FC_NBLK; j += 256) {
    float vv = pvb[(size_t)r * FC_NBLK + j];
    int ii = pib[(size_t)r * FC_NBLK + j];
    if (vv > v || (vv == v && ii < ix)) { v = vv; ix = ii; }
  }
  rv[tid] = v; ri[tid] = ix;
  __syncthreads();
  for (int s = 128; s > 0; s >>= 1) {
    if (tid < s) {
      float v2 = rv[tid + s]; int i2 = ri[tid + s];
      if (v2 > rv[tid] || (v2 == rv[tid] && i2 < ri[tid])) { rv[tid] = v2; ri[tid] = i2; }
    }
    __syncthreads();
  }
  if (tid == 0) s_tok = ri[0];
  __syncthreads();
  const int tok = s_tok;
  float4 vv = ((const float4*)(emb + (size_t)tok * HID))[tid];
  ushort4 h4, l4;
  split2(vv.x, h4.x, l4.x); split2(vv.y, h4.y, l4.y);
  split2(vv.z, h4.z, l4.z); split2(vv.w, h4.w, l4.w);
  ((ushort4*)(xhi + (size_t)r * HID))[tid] = h4;
  ((ushort4*)(xlo + (size_t)r * HID))[tid] = l4;
}

// ---------------- FC GEMM + logits + argmax partials, with fused gh(t+1) ----------------
// grid 884: blocks 0..499 FC tile (64 cols, 4 waves = K-quarters);
//           blocks 500..883 gh tile (only when do_gh)
__global__ __launch_bounds__(256, 2) void k_fc(
    const unsigned short* __restrict__ ahi, const unsigned short* __restrict__ alo,
    const unsigned short* __restrict__ fwhi, const unsigned short* __restrict__ fwlo,
    const float* __restrict__ fc_b, float* __restrict__ out,
    float* __restrict__ pvb, int* __restrict__ pib,
    const unsigned short* __restrict__ whhhi, const unsigned short* __restrict__ whhlo,
    float* __restrict__ gbuf, int t, int do_gh) {
  __shared__ float pred[4][64][68];
  const int bid = blockIdx.x;
  const int tid = threadIdx.x;
  if (bid >= FC_NBLK) {
    if (do_gh) {
      const int g2 = bid - FC_NBLK;
      gates_tile(ahi, alo, whhhi, whhlo, gbuf + (size_t)(8 + (g2 & 7)) * 64 * 3072,
                 g2 >> 3, g2 & 7, tid);
    }
    return;
  }
  const int wv = tid >> 6;            // K-quarter id
  const int lane = tid & 63;
  const int l15 = lane & 15;
  const int kg = (lane >> 4) * 8;
  const int kb = wv * 256 + kg;
  const int c0 = bid * 64;
  const unsigned short* bph = fwhi + (size_t)(c0 + l15) * HID + kb;
  const unsigned short* bpl = fwlo + (size_t)(c0 + l15) * HID + kb;
  const unsigned short* aph = ahi + (size_t)l15 * HID + kb;
  const unsigned short* apl = alo + (size_t)l15 * HID + kb;
  f32x4 acc[4][4] = {};   // [m rows][n cols]
  bf16x8 bh[4], bl[4];
#pragma unroll
  for (int n = 0; n < 4; n++) {
    bh[n] = *(const bf16x8*)(bph + (size_t)n * 16 * HID);
    bl[n] = *(const bf16x8*)(bpl + (size_t)n * 16 * HID);
  }
#pragma unroll 1
  for (int k0 = 0; k0 < 256; k0 += 32) {
    bf16x8 nbh[4], nbl[4];
    if (k0 + 32 < 256) {
#pragma unroll
      for (int n = 0; n < 4; n++) {
        nbh[n] = *(const bf16x8*)(bph + (size_t)n * 16 * HID + k0 + 32);
        nbl[n] = *(const bf16x8*)(bpl + (size_t)n * 16 * HID + k0 + 32);
      }
    }
#pragma unroll
    for (int m = 0; m < 4; m++) {
      bf16x8 a1 = *(const bf16x8*)(aph + (size_t)m * 16 * HID + k0);
      bf16x8 a2 = *(const bf16x8*)(apl + (size_t)m * 16 * HID + k0);
#pragma unroll
      for (int n = 0; n < 4; n++) {
        acc[m][n] = __builtin_amdgcn_mfma_f32_16x16x32_bf16(a1, bh[n], acc[m][n], 0, 0, 0);
        acc[m][n] = __builtin_amdgcn_mfma_f32_16x16x32_bf16(a2, bh[n], acc[m][n], 0, 0, 0);
        acc[m][n] = __builtin_amdgcn_mfma_f32_16x16x32_bf16(a1, bl[n], acc[m][n], 0, 0, 0);
      }
    }
#pragma unroll
    for (int n = 0; n < 4; n++) { bh[n] = nbh[n]; bl[n] = nbl[n]; }
  }
  // dump K-quarter partials to LDS
#pragma unroll
  for (int m = 0; m < 4; m++)
#pragma unroll
    for (int n = 0; n < 4; n++)
#pragma unroll
      for (int q = 0; q < 4; q++)
        pred[wv][m * 16 + (lane >> 4) * 4 + q][n * 16 + l15] = acc[m][n][q];
  __syncthreads();
  // epilogue: thread -> row = tid>>2, col quadrant = (tid&3)*16
  const int row = tid >> 2;
  const int cq = (tid & 3) * 16;
  float v[16];
#pragma unroll
  for (int c4 = 0; c4 < 4; c4++) {
    float4 s0 = *(const float4*)&pred[0][row][cq + c4 * 4];
    float4 s1 = *(const float4*)&pred[1][row][cq + c4 * 4];
    float4 s2 = *(const float4*)&pred[2][row][cq + c4 * 4];
    float4 s3 = *(const float4*)&pred[3][row][cq + c4 * 4];
    v[c4 * 4 + 0] = s0.x + s1.x + s2.x + s3.x + fc_b[c0 + cq + c4 * 4 + 0];
    v[c4 * 4 + 1] = s0.y + s1.y + s2.y + s3.y + fc_b[c0 + cq + c4 * 4 + 1];
    v[c4 * 4 + 2] = s0.z + s1.z + s2.z + s3.z + fc_b[c0 + cq + c4 * 4 + 2];
    v[c4 * 4 + 3] = s0.w + s1.w + s2.w + s3.w + fc_b[c0 + cq + c4 * 4 + 3];
  }
  float* op = out + ((size_t)row * TLEN + t) * VOCAB + c0 + cq;
#pragma unroll
  for (int c = 0; c < 16; c += 4)
    *(float4*)(op + c) = make_float4(v[c], v[c + 1], v[c + 2], v[c + 3]);
  // per-thread argmax over its 16 cols (ascending keeps smallest index on ties)
  float bv = v[0]; int bi = c0 + cq;
#pragma unroll
  for (int c = 1; c < 16; c++)
    if (v[c] > bv) { bv = v[c]; bi = c0 + cq + c; }
#pragma unroll
  for (int d = 1; d < 4; d <<= 1) {
    float ov = __shfl_xor(bv, d);
    int oi = __shfl_xor(bi, d);
    if (ov > bv || (ov == bv && oi < bi)) { bv = ov; bi = oi; }
  }
  if ((tid & 3) == 0) {
    pvb[(size_t)row * FC_NBLK + bid] = bv;
    pib[(size_t)row * FC_NBLK + bid] = bi;
  }
}

// ======================= fp32 fallback path (round-1, known-good) =======================
#define O_FC_NCB 250
#define O_X2T_OFF  0
#define O_GBUF_OFF (2048*64)
#define O_PV_OFF   (O_GBUF_OFF + 8*64*4096)
#define O_PI_OFF   (O_PV_OFF + 64*O_FC_NCB)

__global__ __launch_bounds__(256) void o_prep(
    const float* __restrict__ enc, const int* __restrict__ tt,
    const float* __restrict__ emb, float* __restrict__ X2T,
    const float* __restrict__ pv, const int* __restrict__ pi, int t) {
  const int r = blockIdx.x;
  const int tid = threadIdx.x;
  __shared__ int s_tok;
  __shared__ float red_v[256];
  __shared__ int red_i[256];
  if (t == 0) {
    if (tid == 0) s_tok = tt[r * TLEN];
  } else {
    float v = -INFINITY; int idx = 0x7fffffff;
    if (tid < O_FC_NCB) { v = pv[r * O_FC_NCB + tid]; idx = pi[r * O_FC_NCB + tid]; }
    red_v[tid] = v; red_i[tid] = idx;
    __syncthreads();
    for (int s = 128; s > 0; s >>= 1) {
      if (tid < s) {
        float v2 = red_v[tid + s]; int i2 = red_i[tid + s];
        if (v2 > red_v[tid] || (v2 == red_v[tid] && i2 < red_i[tid])) {
          red_v[tid] = v2; red_i[tid] = i2;
        }
      }
      __syncthreads();
    }
    if (tid == 0) s_tok = red_i[0];
  }
  __syncthreads();
  const int tok = s_tok;
  for (int k = tid; k < HID; k += 256)
    X2T[(size_t)k * 64 + r] = emb[(size_t)tok * HID + k];
  if (t == 0) {
    for (int k = tid; k < HID; k += 256)
      X2T[(size_t)(HID + k) * 64 + r] = enc[r * HID + k];
  }
}

__global__ __launch_bounds__(256) void o_gates(
    const float* __restrict__ w_ih, const float* __restrict__ w_hh,
    const float* __restrict__ X2T, float* __restrict__ gbuf) {
  const int cb = blockIdx.x & 31;
  const int s  = blockIdx.x >> 5;
  const int g  = cb >> 3;
  if (g == 2 && s >= 4) return;
  if (g == 3 && s < 4) return;
  const int tid  = threadIdx.x;
  const int w    = __builtin_amdgcn_readfirstlane(tid >> 6);
  const int lane = tid & 63;
  const int r0   = (w >> 1) * 32;
  const int cc   = cb * 128 + (w & 1) * 64 + lane;
  const int j    = cc & 1023;
  const float* Bmat; int kk0;
  if (s < 4) { Bmat = w_ih; kk0 = s * 256; }
  else       { Bmat = w_hh; kk0 = (s - 4) * 256; }
  int brow;
  if (g == 0) brow = j;
  else if (g == 1) brow = 1024 + j;
  else brow = 2048 + j;
  const float* Bp = Bmat + (size_t)brow * HID + kk0;
  const float* Ap = X2T + (size_t)(s * 256) * 64 + r0;
  float acc[32];
#pragma unroll
  for (int i = 0; i < 32; i++) acc[i] = 0.f;
  for (int k = 0; k < 256; k += 4) {
    float4 b = *(const float4*)(Bp + k);
#pragma unroll
    for (int kk = 0; kk < 4; kk++) {
      const float bk = (&b.x)[kk];
      const float* a = Ap + (size_t)(k + kk) * 64;
#pragma unroll
      for (int i = 0; i < 32; i++) acc[i] = fmaf(a[i], bk, acc[i]);
    }
  }
  float* C = gbuf + (size_t)s * (64 * 4096) + cc;
#pragma unroll
  for (int i = 0; i < 32; i++) C[(size_t)(r0 + i) * 4096] = acc[i];
}

__global__ __launch_bounds__(256) void o_combine(
    const float* __restrict__ b_ih, const float* __restrict__ b_hh,
    const float* __restrict__ gbuf, float* __restrict__ X2T) {
  const int idx = blockIdx.x * 256 + threadIdx.x;
  const int r = idx >> 10;
  const int j = idx & 1023;
  const size_t SS = (size_t)64 * 4096;
  float sr  = b_ih[j] + b_hh[j];
  float sz  = b_ih[1024 + j] + b_hh[1024 + j];
  float inn = b_ih[2048 + j];
  float hn  = b_hh[2048 + j];
#pragma unroll
  for (int s = 0; s < 8; s++) {
    const float* gs = gbuf + s * SS + (size_t)r * 4096;
    sr += gs[j];
    sz += gs[1024 + j];
    if (s < 4) inn += gs[2048 + j]; else hn += gs[3072 + j];
  }
  float rg = 1.f / (1.f + expf(-sr));
  float zg = 1.f / (1.f + expf(-sz));
  float n  = tanhf(inn + rg * hn);
  float hp = X2T[(size_t)(1024 + j) * 64 + r];
  float h  = (1.f - zg) * n + zg * hp;
  X2T[(size_t)(1024 + j) * 64 + r] = h;
}

__global__ __launch_bounds__(256) void o_fc(
    const float* __restrict__ fc_w, const float* __restrict__ fc_b,
    const float* __restrict__ hT, float* __restrict__ out,
    float* __restrict__ pv, int* __restrict__ pi, int t) {
  const int tid  = threadIdx.x;
  const int w    = __builtin_amdgcn_readfirstlane(tid >> 6);
  const int lane = tid & 63;
  const int r0   = (w >> 1) * 32;
  const int col  = blockIdx.x * 128 + (w & 1) * 64 + lane;
  const float* Bp = fc_w + (size_t)col * HID;
  float acc[32];
#pragma unroll
  for (int i = 0; i < 32; i++) acc[i] = 0.f;
  for (int k = 0; k < HID; k += 4) {
    float4 b = *(const float4*)(Bp + k);
#pragma unroll
    for (int kk = 0; kk < 4; kk++) {
      const float bk = (&b.x)[kk];
      const float* a = hT + (size_t)(k + kk) * 64 + r0;
#pragma unroll
      for (int i = 0; i < 32; i++) acc[i] = fmaf(a[i], bk, acc[i]);
    }
  }
  const float bias = fc_b[col];
#pragma unroll
  for (int i = 0; i < 32; i++) {
    float v = acc[i] + bias;
    acc[i] = v;
    out[((size_t)(r0 + i) * TLEN + t) * VOCAB + col] = v;
  }
  __shared__ float sv[2][64];
  __shared__ int   si[2][64];
#pragma unroll 4
  for (int i = 0; i < 32; i++) {
    float v = acc[i]; int idx = col;
#pragma unroll
    for (int d = 32; d > 0; d >>= 1) {
      float v2 = __shfl_xor(v, d);
      int i2   = __shfl_xor(idx, d);
      if (v2 > v || (v2 == v && i2 < idx)) { v = v2; idx = i2; }
    }
    if (lane == 0) { sv[w & 1][r0 + i] = v; si[w & 1][r0 + i] = idx; }
  }
  __syncthreads();
  if (tid < 64) {
    float v = sv[0][tid]; int idx = si[0][tid];
    float v2 = sv[1][tid]; int i2 = si[1][tid];
    if (v2 > v || (v2 == v && i2 < idx)) { v = v2; idx = i2; }
    pv[tid * O_FC_NCB + blockIdx.x] = v;
    pi[tid * O_FC_NCB + blockIdx.x] = idx;
  }
}

// =======================================================================
extern "C" void kernel_launch(void* const* d_in, const int* in_sizes, int n_in,
                              void* d_out, int out_size, void* d_ws, size_t ws_size,
                              hipStream_t stream) {
  const float* enc  = (const float*)d_in[0];
  const int*   tt   = (const int*)d_in[1];
  const float* emb  = (const float*)d_in[2];
  const float* w_ih = (const float*)d_in[3];
  const float* w_hh = (const float*)d_in[4];
  const float* b_ih = (const float*)d_in[5];
  const float* b_hh = (const float*)d_in[6];
  const float* fc_w = (const float*)d_in[7];
  const float* fc_b = (const float*)d_in[8];
  float* out = (float*)d_out;

  if (ws_size >= WS_NEED) {
    char* ws = (char*)d_ws;
    unsigned short* fcw_hi = (unsigned short*)(ws + OFF_FCW_HI);
    unsigned short* fcw_lo = (unsigned short*)(ws + OFF_FCW_LO);
    unsigned short* wih_hi = (unsigned short*)(ws + OFF_WIH_HI);
    unsigned short* wih_lo = (unsigned short*)(ws + OFF_WIH_LO);
    unsigned short* whh_hi = (unsigned short*)(ws + OFF_WHH_HI);
    unsigned short* whh_lo = (unsigned short*)(ws + OFF_WHH_LO);
    float* gbuf = (float*)(ws + OFF_GBUF);
    float* h32  = (float*)(ws + OFF_H32);
    unsigned short* xhi = (unsigned short*)(ws + OFF_XHI);
    unsigned short* xlo = (unsigned short*)(ws + OFF_XLO);
    unsigned short* hhi = (unsigned short*)(ws + OFF_HHI);
    unsigned short* hlo = (unsigned short*)(ws + OFF_HLO);
    float* pvb = (float*)(ws + OFF_PVB);
    int*   pib = (int*)(ws + OFF_PIB);

    k_split<<<4096, 256, 0, stream>>>(fc_w, fcw_hi, fcw_lo, VOCAB * HID / 4);
    k_split<<<1536, 256, 0, stream>>>(w_ih, wih_hi, wih_lo, 3 * HID * HID / 4);
    k_split<<<1536, 256, 0, stream>>>(w_hh, whh_hi, whh_lo, 3 * HID * HID / 4);
    k_init<<<64, 256, 0, stream>>>(enc, tt, emb, xhi, xlo, h32, hhi, hlo);
    k_gi<<<GH_NBLK, 256, 0, stream>>>(xhi, xlo, wih_hi, wih_lo, gbuf);
    k_gh<<<GH_NBLK, 256, 0, stream>>>(hhi, hlo, whh_hi, whh_lo, gbuf);

    for (int t = 0; t < TLEN; t++) {
      k_combine<<<256, 256, 0, stream>>>(gbuf, b_ih, b_hh, h32, hhi, hlo);
      k_fc<<<FC_NBLK + GH_NBLK, 256, 0, stream>>>(hhi, hlo, fcw_hi, fcw_lo, fc_b, out,
                                                  pvb, pib, whh_hi, whh_lo, gbuf, t,
                                                  (t < TLEN - 1) ? 1 : 0);
      if (t < TLEN - 1) {
        k_prep<<<64, 256, 0, stream>>>(pvb, pib, emb, xhi, xlo);
        k_gi<<<GH_NBLK, 256, 0, stream>>>(xhi, xlo, wih_hi, wih_lo, gbuf);
      }
    }
  } else {
    float* ws = (float*)d_ws;
    float* X2T  = ws + O_X2T_OFF;
    float* gbuf = ws + O_GBUF_OFF;
    float* pv   = ws + O_PV_OFF;
    int*   pi   = (int*)(ws + O_PI_OFF);
    for (int t = 0; t < TLEN; t++) {
      o_prep<<<64, 256, 0, stream>>>(enc, tt, emb, X2T, pv, pi, t);
      o_gates<<<256, 256, 0, stream>>>(w_ih, w_hh, X2T, gbuf);
      o_combine<<<256, 256, 0, stream>>>(b_ih, b_hh, gbuf, X2T);
      o_fc<<<O_FC_NCB, 256, 0, stream>>>(fc_w, fc_b, X2T + (size_t)HID * 64, out, pv, pi, t);
    }
  }
}